// Round 1
// baseline (105.512 us; speedup 1.0000x reference)
//
#include <hip/hip_runtime.h>

// Problem constants
#define NN 1024
#define DD 64
#define HH 8

// ---------------------------------------------------------------------------
// rc[(k*2+t)*8192 + n*8 + h] = sum_d idx_emb[n,d] * W1[k,h, 1 + t*64 + d]
// t=0: row (w_i), t=1: col (w_j)
__global__ void k_rowcol(const float* __restrict__ idx_emb,
                         const float* __restrict__ msg_W1,
                         float* __restrict__ rc) {
    int tid = blockIdx.x * 256 + threadIdx.x;      // 32768 total
    int h  = tid & 7;
    int n  = (tid >> 3) & 1023;
    int t_ = (tid >> 13) & 1;
    int k  = tid >> 14;
    const float* w = msg_W1 + k * 1032 + h * 129 + 1 + t_ * 64;
    const float* e = idx_emb + n * 64;
    float s = 0.f;
#pragma unroll
    for (int d = 0; d < 64; ++d) s += e[d] * w[d];
    rc[(k * 2 + t_) * 8192 + n * 8 + h] = s;
}

// ---------------------------------------------------------------------------
// tg[j] = mean_n t_grad[n, j]
__global__ void k_tg(const float* __restrict__ t_grad, float* __restrict__ tg) {
    __shared__ float red[4][64];
    int jl = threadIdx.x & 63, s = threadIdx.x >> 6;
    int j = blockIdx.x * 64 + jl;
    float acc = 0.f;
    for (int i = 0; i < 256; ++i) acc += t_grad[(s * 256 + i) * 1024 + j];
    red[s][jl] = acc;
    __syncthreads();
    if (s == 0)
        tg[j] = (red[0][jl] + red[1][jl] + red[2][jl] + red[3][jl]) * (1.0f / 1024.0f);
}

// ---------------------------------------------------------------------------
// Per-pair message MLP. grid (1024, 2): n = bx, k = by. 256 threads, 4 m each.
__global__ __launch_bounds__(256) void k_msg(
    const float* __restrict__ adj, const float* __restrict__ adj_deriv,
    const float* __restrict__ W1, const float* __restrict__ b1,
    const float* __restrict__ W2, const float* __restrict__ b2,
    const float* __restrict__ W3, const float* __restrict__ b3,
    const float* __restrict__ rc,
    float* __restrict__ a_out, float* __restrict__ ad_out) {
    int n = blockIdx.x, k = blockIdx.y;
    const float* A = (k == 0) ? adj : adj_deriv;
    float* O = (k == 0) ? a_out : ad_out;
    const float* W1k = W1 + k * 1032;

    float wa[8], b1v[8], w2[64], b2v[8], w3v[8], rown[8];
#pragma unroll
    for (int h = 0; h < 8; ++h) {
        wa[h]   = W1k[h * 129];
        b1v[h]  = b1[k * 8 + h];
        b2v[h]  = b2[k * 8 + h];
        w3v[h]  = W3[k * 8 + h];
        rown[h] = rc[(k * 2) * 8192 + n * 8 + h];
    }
#pragma unroll
    for (int i = 0; i < 64; ++i) w2[i] = W2[k * 64 + i];
    float b3v = b3[k];
    const float* col = rc + (k * 2 + 1) * 8192;

    for (int it = 0; it < 4; ++it) {
        int m = threadIdx.x + it * 256;
        float av = A[n * 1024 + m];
        float h1[8];
#pragma unroll
        for (int h = 0; h < 8; ++h) {
            float v = av * wa[h] + rown[h] + col[m * 8 + h] + b1v[h];
            h1[h] = v > 0.f ? v : 0.f;
        }
        float o = b3v;
#pragma unroll
        for (int kk = 0; kk < 8; ++kk) {
            float s = b2v[kk];
#pragma unroll
            for (int h = 0; h < 8; ++h) s += h1[h] * w2[kk * 8 + h];
            s = s > 0.f ? s : 0.f;
            o += s * w3v[kk];
        }
        O[n * 1024 + m] = o;
    }
}

// ---------------------------------------------------------------------------
// u_j = x @ W_j  (1024x64)@(64x64), j = blockIdx.y in [0,5). grid (256,5).
__global__ __launch_bounds__(256) void k_xw(const float* __restrict__ x,
                                            const float* __restrict__ W,
                                            float* __restrict__ u) {
    int j = blockIdx.y;
    int n0 = blockIdx.x * 4;
    __shared__ float xs[4][64];
    int c = threadIdx.x & 63, nl = threadIdx.x >> 6;
    xs[nl][c] = x[(n0 + nl) * 64 + c];
    __syncthreads();
    const float* Wj = W + j * 4096;
    float acc = 0.f;
#pragma unroll 8
    for (int d = 0; d < 64; ++d) acc += xs[nl][d] * Wj[d * 64 + c];
    u[j * 65536 + (n0 + nl) * 64 + c] = acc;
}

// ---------------------------------------------------------------------------
// P[split][n][c] partial of  a@u0 + aT@u1 + ad@u2 + adT@u3  over m-range.
// grid (32 n-tiles, 16 m-splits), block 256. Tile: 32n x 64c, m-chunk 32.
__global__ __launch_bounds__(256) void k_spmm(const float* __restrict__ a,
                                              const float* __restrict__ ad,
                                              const float* __restrict__ u,
                                              float* __restrict__ P) {
    int n0 = blockIdx.x * 32;
    int ms = blockIdx.y * 64;   // this block's m range: [ms, ms+64), 2 chunks of 32
    __shared__ float ar[32][33], ac[32][33], dr[32][33], dc[32][33];
    __shared__ float us[4][32][64];
    int t = threadIdx.x;
    int cg = t & 15, ng = t >> 4;   // c0 = cg*4 ; n locals: ng, ng+16
    int c0 = cg * 4;
    float acc[2][4] = {};

    for (int ch = 0; ch < 2; ++ch) {
        int mc = ms + ch * 32;
        __syncthreads();
        {   // row tiles: a[n0+i][mc+j] -> ar[j][i]   (coalesced along j)
            int j = t & 31, i0 = t >> 5;
#pragma unroll
            for (int p = 0; p < 4; ++p) {
                int i = i0 + p * 8;
                ar[j][i] = a[(n0 + i) * 1024 + mc + j];
                dr[j][i] = ad[(n0 + i) * 1024 + mc + j];
            }
            // col tiles: a[mc+jj][n0+i] -> ac[jj][i]  (coalesced along i)
            int i = t & 31, j0 = t >> 5;
#pragma unroll
            for (int p = 0; p < 4; ++p) {
                int jj = j0 + p * 8;
                ac[jj][i] = a[(mc + jj) * 1024 + n0 + i];
                dc[jj][i] = ad[(mc + jj) * 1024 + n0 + i];
            }
        }
        {   // u tiles
            int c = t & 63, r0 = t >> 6;
#pragma unroll
            for (int jj = 0; jj < 4; ++jj)
#pragma unroll
                for (int p = 0; p < 8; ++p) {
                    int m = r0 + p * 4;
                    us[jj][m][c] = u[jj * 65536 + (mc + m) * 64 + c];
                }
        }
        __syncthreads();
#pragma unroll 4
        for (int m = 0; m < 32; ++m) {
            float4 u0 = *(const float4*)&us[0][m][c0];
            float4 u1 = *(const float4*)&us[1][m][c0];
            float4 u2 = *(const float4*)&us[2][m][c0];
            float4 u3 = *(const float4*)&us[3][m][c0];
#pragma unroll
            for (int ni = 0; ni < 2; ++ni) {
                int nn = ng + ni * 16;
                float va = ar[m][nn], vc = ac[m][nn];
                float vd = dr[m][nn], ve = dc[m][nn];
                acc[ni][0] += va * u0.x + vc * u1.x + vd * u2.x + ve * u3.x;
                acc[ni][1] += va * u0.y + vc * u1.y + vd * u2.y + ve * u3.y;
                acc[ni][2] += va * u0.z + vc * u1.z + vd * u2.z + ve * u3.z;
                acc[ni][3] += va * u0.w + vc * u1.w + vd * u2.w + ve * u3.w;
            }
        }
    }
    float* Ps = P + blockIdx.y * 65536;
#pragma unroll
    for (int ni = 0; ni < 2; ++ni) {
        int nn = n0 + ng + ni * 16;
        *(float4*)&Ps[nn * 64 + c0] =
            make_float4(acc[ni][0], acc[ni][1], acc[ni][2], acc[ni][3]);
    }
}

// ---------------------------------------------------------------------------
// out = [relu]( sum_s P[s] + u4 + b ) [* tg[n]]
__global__ void k_reduce(const float* __restrict__ P, const float* __restrict__ u4,
                         const float* __restrict__ b, const float* __restrict__ tg,
                         float* __restrict__ out, int do_relu, int do_tg) {
    int idx = blockIdx.x * 256 + threadIdx.x;
    int n = idx >> 6, c = idx & 63;
    float s = u4[idx] + b[c];
#pragma unroll
    for (int k = 0; k < 16; ++k) s += P[k * 65536 + idx];
    if (do_relu) s = fmaxf(s, 0.f);
    if (do_tg) s *= tg[n];
    out[idx] = s;
}

// ---------------------------------------------------------------------------
extern "C" void kernel_launch(void* const* d_in, const int* in_sizes, int n_in,
                              void* d_out, int out_size, void* d_ws, size_t ws_size,
                              hipStream_t stream) {
    const float* y         = (const float*)d_in[0];
    const float* adj       = (const float*)d_in[1];
    const float* adj_deriv = (const float*)d_in[2];
    const float* t_grad    = (const float*)d_in[3];
    const float* idx_emb   = (const float*)d_in[4];
    const float* msg_W1    = (const float*)d_in[5];
    const float* msg_b1    = (const float*)d_in[6];
    const float* msg_W2    = (const float*)d_in[7];
    const float* msg_b2    = (const float*)d_in[8];
    const float* msg_W3    = (const float*)d_in[9];
    const float* msg_b3    = (const float*)d_in[10];
    const float* gnn_W     = (const float*)d_in[11];
    const float* gnn_b     = (const float*)d_in[12];

    float* ws  = (float*)d_ws;
    float* a_  = ws;              // 1048576
    float* ad_ = ws + 1048576;    // 1048576
    float* rc  = ws + 2097152;    // 32768
    float* tg  = ws + 2129920;    // 1024
    float* u   = ws + 2130944;    // 5*65536 = 327680
    float* P   = ws + 2458624;    // 16*65536 = 1048576
    float* x0  = ws + 3507200;    // 65536
    float* x1  = ws + 3572736;    // 65536  (end: 3638272 floats = 14.6 MB)

    k_rowcol<<<128, 256, 0, stream>>>(idx_emb, msg_W1, rc);
    k_tg<<<16, 256, 0, stream>>>(t_grad, tg);
    k_msg<<<dim3(1024, 2), 256, 0, stream>>>(adj, adj_deriv, msg_W1, msg_b1,
                                             msg_W2, msg_b2, msg_W3, msg_b3,
                                             rc, a_, ad_);

    const float* xin = y;
    for (int l = 0; l < 3; ++l) {
        float* xout = (l == 2) ? (float*)d_out : ((l == 0) ? x0 : x1);
        k_xw<<<dim3(256, 5), 256, 0, stream>>>(xin, gnn_W + l * 5 * 4096, u);
        k_spmm<<<dim3(32, 16), 256, 0, stream>>>(a_, ad_, u, P);
        k_reduce<<<256, 256, 0, stream>>>(P, u + 4 * 65536, gnn_b + l * 64, tg,
                                          xout, (l < 2) ? 1 : 0, (l == 2) ? 1 : 0);
        xin = xout;
    }
}

// Round 2
// 95.777 us; speedup vs baseline: 1.1016x; 1.1016x over previous
//
#include <hip/hip_runtime.h>

typedef __attribute__((ext_vector_type(8))) short bf16x8;
typedef __attribute__((ext_vector_type(4))) float f32x4;

__device__ __forceinline__ unsigned short f2bf(float f) {
    unsigned int u = __builtin_bit_cast(unsigned int, f);
    unsigned int r = (u + 0x7fffu + ((u >> 16) & 1u)) >> 16;
    return (unsigned short)r;
}

// ---------------------------------------------------------------------------
// rc[(k*2+t)*8192 + n*8 + h] = sum_d idx_emb[n,d] * W1[k,h, 1 + t*64 + d]
__global__ void k_rowcol(const float* __restrict__ idx_emb,
                         const float* __restrict__ msg_W1,
                         float* __restrict__ rc) {
    int tid = blockIdx.x * 256 + threadIdx.x;      // 32768 total
    int h  = tid & 7;
    int n  = (tid >> 3) & 1023;
    int t_ = (tid >> 13) & 1;
    int k  = tid >> 14;
    const float* w = msg_W1 + k * 1032 + h * 129 + 1 + t_ * 64;
    const float* e = idx_emb + n * 64;
    float s = 0.f;
#pragma unroll
    for (int d = 0; d < 64; ++d) s += e[d] * w[d];
    rc[(k * 2 + t_) * 8192 + n * 8 + h] = s;
}

// ---------------------------------------------------------------------------
__global__ void k_tg(const float* __restrict__ t_grad, float* __restrict__ tg) {
    __shared__ float red[4][64];
    int jl = threadIdx.x & 63, s = threadIdx.x >> 6;
    int j = blockIdx.x * 64 + jl;
    float acc = 0.f;
    for (int i = 0; i < 256; ++i) acc += t_grad[(s * 256 + i) * 1024 + j];
    red[s][jl] = acc;
    __syncthreads();
    if (s == 0)
        tg[j] = (red[0][jl] + red[1][jl] + red[2][jl] + red[3][jl]) * (1.0f / 1024.0f);
}

// ---------------------------------------------------------------------------
// Per-pair message MLP. grid (1024, 2): n = bx, k = by.
__global__ __launch_bounds__(256) void k_msg(
    const float* __restrict__ adj, const float* __restrict__ adj_deriv,
    const float* __restrict__ W1, const float* __restrict__ b1,
    const float* __restrict__ W2, const float* __restrict__ b2,
    const float* __restrict__ W3, const float* __restrict__ b3,
    const float* __restrict__ rc,
    float* __restrict__ a_out, float* __restrict__ ad_out) {
    int n = blockIdx.x, k = blockIdx.y;
    const float* A = (k == 0) ? adj : adj_deriv;
    float* O = (k == 0) ? a_out : ad_out;
    const float* W1k = W1 + k * 1032;

    float wa[8], b1v[8], w2[64], b2v[8], w3v[8], rown[8];
#pragma unroll
    for (int h = 0; h < 8; ++h) {
        wa[h]   = W1k[h * 129];
        b1v[h]  = b1[k * 8 + h];
        b2v[h]  = b2[k * 8 + h];
        w3v[h]  = W3[k * 8 + h];
        rown[h] = rc[(k * 2) * 8192 + n * 8 + h];
    }
#pragma unroll
    for (int i = 0; i < 64; ++i) w2[i] = W2[k * 64 + i];
    float b3v = b3[k];
    const float* col = rc + (k * 2 + 1) * 8192;

    for (int it = 0; it < 4; ++it) {
        int m = threadIdx.x + it * 256;
        float av = A[n * 1024 + m];
        float h1[8];
#pragma unroll
        for (int h = 0; h < 8; ++h) {
            float v = av * wa[h] + rown[h] + col[m * 8 + h] + b1v[h];
            h1[h] = v > 0.f ? v : 0.f;
        }
        float o = b3v;
#pragma unroll
        for (int kk = 0; kk < 8; ++kk) {
            float s = b2v[kk];
#pragma unroll
            for (int h = 0; h < 8; ++h) s += h1[h] * w2[kk * 8 + h];
            s = s > 0.f ? s : 0.f;
            o += s * w3v[kk];
        }
        O[n * 1024 + m] = o;
    }
}

// ---------------------------------------------------------------------------
// Transpose + convert: Abf = [a | aT | ad | adT], each 1024x1024 bf16 row-major.
// grid (16,16,2), block 256. Tile 64x64.
__global__ __launch_bounds__(256) void k_cvtA(const float* __restrict__ a,
                                              const float* __restrict__ ad,
                                              unsigned short* __restrict__ Abf) {
    __shared__ float tile[64][65];
    int bx = blockIdx.x, by = blockIdx.y, z = blockIdx.z;
    const float* S = z ? ad : a;
    unsigned short* D0 = Abf + z * 2097152;        // row-major
    unsigned short* D1 = D0 + 1048576;             // transposed
    int c = threadIdx.x & 63, r0 = threadIdx.x >> 6;
#pragma unroll
    for (int p = 0; p < 16; ++p) {
        int r = r0 + p * 4;
        float v = S[(by * 64 + r) * 1024 + bx * 64 + c];
        tile[r][c] = v;
        D0[(by * 64 + r) * 1024 + bx * 64 + c] = f2bf(v);
    }
    __syncthreads();
#pragma unroll
    for (int p = 0; p < 16; ++p) {
        int r = r0 + p * 4;
        D1[(bx * 64 + r) * 1024 + by * 64 + c] = f2bf(tile[c][r]);
    }
}

// ---------------------------------------------------------------------------
// u_j = x @ W_j. j<4: write uT bf16 [j][64 c][1024 m]; j==4: fp32 u4[n][c].
// grid (16, 5), block 256.
__global__ __launch_bounds__(256) void k_xw2(const float* __restrict__ x,
                                             const float* __restrict__ W,
                                             float* __restrict__ u4,
                                             unsigned short* __restrict__ uT) {
    int mt = blockIdx.x, j = blockIdx.y;
    __shared__ float xs[64][65];
    int c = threadIdx.x & 63, r0 = threadIdx.x >> 6;
#pragma unroll
    for (int p = 0; p < 16; ++p) {
        int r = r0 + p * 4;
        xs[r][c] = x[(mt * 64 + r) * 64 + c];
    }
    __syncthreads();
    const float* Wj = W + j * 4096;
    float acc[16] = {};
    for (int d = 0; d < 64; ++d) {
        float wv = Wj[d * 64 + c];
#pragma unroll
        for (int p = 0; p < 16; ++p) acc[p] += xs[r0 + p * 4][d] * wv;
    }
    if (j == 4) {
#pragma unroll
        for (int p = 0; p < 16; ++p) u4[(mt * 64 + r0 + p * 4) * 64 + c] = acc[p];
    } else {
        __syncthreads();
#pragma unroll
        for (int p = 0; p < 16; ++p) xs[r0 + p * 4][c] = acc[p];
        __syncthreads();
        unsigned short* D = uT + j * 65536;
#pragma unroll
        for (int p = 0; p < 16; ++p) {
            int cc = r0 + p * 4;
            D[cc * 1024 + mt * 64 + c] = f2bf(xs[c][cc]);
        }
    }
}

// ---------------------------------------------------------------------------
// MFMA GEMM: P[ms][n][c] = sum_j sum_{m in block range} Aj[n][m] * uj[m][c]
// grid (16 n-tiles, 16 m-splits), block 256 (4 waves), wave = 16 rows.
// Fragments loaded directly from global (L2-resident), contiguous-8 k per lane.
__global__ __launch_bounds__(256) void k_gemm(const unsigned short* __restrict__ Abf,
                                              const unsigned short* __restrict__ uT,
                                              float* __restrict__ P) {
    int nt = blockIdx.x, ms = blockIdx.y;
    int w = threadIdx.x >> 6, l = threadIdx.x & 63;
    int row = nt * 64 + w * 16 + (l & 15);
    int klo = 8 * (l >> 4);
    int m0 = ms * 64;
    f32x4 acc[4];
#pragma unroll
    for (int cf = 0; cf < 4; ++cf) acc[cf] = (f32x4){0.f, 0.f, 0.f, 0.f};

#pragma unroll
    for (int j = 0; j < 4; ++j) {
        const unsigned short* Aj = Abf + j * 1048576;
        const unsigned short* Uj = uT + j * 65536;
#pragma unroll
        for (int kk = 0; kk < 64; kk += 32) {
            int k0 = m0 + kk;
            bf16x8 af = *(const bf16x8*)&Aj[row * 1024 + k0 + klo];
#pragma unroll
            for (int cf = 0; cf < 4; ++cf) {
                bf16x8 bfr = *(const bf16x8*)&Uj[(cf * 16 + (l & 15)) * 1024 + k0 + klo];
                acc[cf] = __builtin_amdgcn_mfma_f32_16x16x32_bf16(af, bfr, acc[cf], 0, 0, 0);
            }
        }
    }
    float* Pp = P + ms * 65536;
    int nbase = nt * 64 + w * 16 + (l >> 4) * 4;
    int c = l & 15;
#pragma unroll
    for (int cf = 0; cf < 4; ++cf)
#pragma unroll
        for (int r = 0; r < 4; ++r)
            Pp[(nbase + r) * 64 + cf * 16 + c] = acc[cf][r];
}

// ---------------------------------------------------------------------------
// out = [relu]( sum_s P[s] + u4 + b ) [* tg[n]]
__global__ void k_reduce(const float* __restrict__ P, const float* __restrict__ u4,
                         const float* __restrict__ b, const float* __restrict__ tg,
                         float* __restrict__ out, int do_relu, int do_tg) {
    int idx = blockIdx.x * 256 + threadIdx.x;
    int n = idx >> 6, c = idx & 63;
    float s = u4[idx] + b[c];
#pragma unroll
    for (int k = 0; k < 16; ++k) s += P[k * 65536 + idx];
    if (do_relu) s = fmaxf(s, 0.f);
    if (do_tg) s *= tg[n];
    out[idx] = s;
}

// ---------------------------------------------------------------------------
extern "C" void kernel_launch(void* const* d_in, const int* in_sizes, int n_in,
                              void* d_out, int out_size, void* d_ws, size_t ws_size,
                              hipStream_t stream) {
    const float* y         = (const float*)d_in[0];
    const float* adj       = (const float*)d_in[1];
    const float* adj_deriv = (const float*)d_in[2];
    const float* t_grad    = (const float*)d_in[3];
    const float* idx_emb   = (const float*)d_in[4];
    const float* msg_W1    = (const float*)d_in[5];
    const float* msg_b1    = (const float*)d_in[6];
    const float* msg_W2    = (const float*)d_in[7];
    const float* msg_b2    = (const float*)d_in[8];
    const float* msg_W3    = (const float*)d_in[9];
    const float* msg_b3    = (const float*)d_in[10];
    const float* gnn_W     = (const float*)d_in[11];
    const float* gnn_b     = (const float*)d_in[12];

    float* ws  = (float*)d_ws;
    float* a_  = ws;                       // 1048576 f
    float* ad_ = ws + 1048576;             // 1048576 f
    float* rc  = ws + 2097152;             // 32768 f
    float* tg  = ws + 2129920;             // 1024 f
    float* u4  = ws + 2130944;             // 65536 f
    float* P   = ws + 2196480;             // 16*65536 = 1048576 f
    float* x0  = ws + 3245056;             // 65536 f
    float* x1  = ws + 3310592;             // 65536 f
    unsigned short* uT  = (unsigned short*)(ws + 3376128);  // 4*65536 us = 131072 f
    unsigned short* Abf = (unsigned short*)(ws + 3507200);  // 4*1048576 us = 2097152 f
    // end: 5604352 floats = 22.4 MB

    k_rowcol<<<128, 256, 0, stream>>>(idx_emb, msg_W1, rc);
    k_tg<<<16, 256, 0, stream>>>(t_grad, tg);
    k_msg<<<dim3(1024, 2), 256, 0, stream>>>(adj, adj_deriv, msg_W1, msg_b1,
                                             msg_W2, msg_b2, msg_W3, msg_b3,
                                             rc, a_, ad_);
    k_cvtA<<<dim3(16, 16, 2), 256, 0, stream>>>(a_, ad_, Abf);

    const float* xin = y;
    for (int l = 0; l < 3; ++l) {
        float* xout = (l == 2) ? (float*)d_out : ((l == 0) ? x0 : x1);
        k_xw2<<<dim3(16, 5), 256, 0, stream>>>(xin, gnn_W + l * 5 * 4096, u4, uT);
        k_gemm<<<dim3(16, 16), 256, 0, stream>>>(Abf, uT, P);
        k_reduce<<<256, 256, 0, stream>>>(P, u4, gnn_b + l * 64, tg,
                                          xout, (l < 2) ? 1 : 0, (l == 2) ? 1 : 0);
        xin = xout;
    }
}

// Round 3
// 66.037 us; speedup vs baseline: 1.5978x; 1.4504x over previous
//
#include <hip/hip_runtime.h>

typedef __attribute__((ext_vector_type(8))) short bf16x8;
typedef __attribute__((ext_vector_type(4))) float f32x4;
typedef __attribute__((ext_vector_type(4))) unsigned short us4;

__device__ __forceinline__ unsigned short f2bf(float f) {
    unsigned int u = __builtin_bit_cast(unsigned int, f);
    unsigned int r = (u + 0x7fffu + ((u >> 16) & 1u)) >> 16;
    return (unsigned short)r;
}

// ---------------------------------------------------------------------------
// Fused independent prep: rc projections, tg mean, y->bf16, W->bf16 transposed.
__global__ __launch_bounds__(256) void k_aux(
    const float* __restrict__ idx_emb, const float* __restrict__ msg_W1,
    float* __restrict__ rc,
    const float* __restrict__ t_grad, float* __restrict__ tg,
    const float* __restrict__ y, unsigned short* __restrict__ xbf,
    const float* __restrict__ gnn_W, unsigned short* __restrict__ WbfT) {
    __shared__ float red[4][64];
    int bx = blockIdx.x, t = threadIdx.x;
    if (bx < 128) {
        int tid = bx * 256 + t;
        int h = tid & 7, n = (tid >> 3) & 1023, t_ = (tid >> 13) & 1, k = tid >> 14;
        const float* wv = msg_W1 + k * 1032 + h * 129 + 1 + t_ * 64;
        const float* e = idx_emb + n * 64;
        float s = 0.f;
#pragma unroll
        for (int d = 0; d < 64; ++d) s += e[d] * wv[d];
        rc[(k * 2 + t_) * 8192 + n * 8 + h] = s;
    } else if (bx < 144) {
        int jl = t & 63, sg = t >> 6;
        int j = (bx - 128) * 64 + jl;
        float acc = 0.f;
        for (int i = 0; i < 256; ++i) acc += t_grad[(sg * 256 + i) * 1024 + j];
        red[sg][jl] = acc;
        __syncthreads();
        if (sg == 0)
            tg[j] = (red[0][jl] + red[1][jl] + red[2][jl] + red[3][jl]) * (1.f / 1024.f);
    } else if (bx < 160) {
        int base = (bx - 144) * 4096 + t;
#pragma unroll
        for (int p = 0; p < 16; ++p) xbf[base + p * 256] = f2bf(y[base + p * 256]);
    } else if (bx < 175) {
        int wi = bx - 160;                      // l*5 + j
        const float* src = gnn_W + wi * 4096;
        unsigned short* dst = WbfT + wi * 4096; // [c][d] = W[d][c]
        int c = t & 63, dg = t >> 6;
#pragma unroll
        for (int p = 0; p < 16; ++p) {
            int d = dg + p * 4;
            dst[c * 64 + d] = f2bf(src[d * 64 + c]);
        }
    }
}

// ---------------------------------------------------------------------------
// Fused msg-MLP + bf16 convert + transpose. grid (16 mt, 16 nt, 2 z).
// Writes Abf[2z] (row-major) and Abf[2z+1] (transposed), each 1024x1024 bf16.
__global__ __launch_bounds__(256) void k_msgcvt(
    const float* __restrict__ adj, const float* __restrict__ adj_deriv,
    const float* __restrict__ W1, const float* __restrict__ b1,
    const float* __restrict__ W2, const float* __restrict__ b2,
    const float* __restrict__ W3, const float* __restrict__ b3,
    const float* __restrict__ rc, unsigned short* __restrict__ Abf) {
    int mt = blockIdx.x, nt = blockIdx.y, z = blockIdx.z;
    const float* A = z ? adj_deriv : adj;
    unsigned short* D0 = Abf + z * 2097152;
    unsigned short* D1 = D0 + 1048576;
    int k = z;

    float wa[8], b1v[8], w2[64], b2v[8], w3v[8];
#pragma unroll
    for (int h = 0; h < 8; ++h) {
        wa[h]  = W1[k * 1032 + h * 129];
        b1v[h] = b1[k * 8 + h];
        b2v[h] = b2[k * 8 + h];
        w3v[h] = W3[k * 8 + h];
    }
#pragma unroll
    for (int i = 0; i < 64; ++i) w2[i] = W2[k * 64 + i];
    float b3v = b3[k];

    int t = threadIdx.x;
    int c = t & 63, rg = t >> 6;
    // column features for this thread's m = mt*64 + c
    const float* colp = rc + (k * 2 + 1) * 8192 + (mt * 64 + c) * 8;
    float cm[8];
    *(float4*)&cm[0] = *(const float4*)colp;
    *(float4*)&cm[4] = *(const float4*)(colp + 4);
    const float* rowp = rc + (k * 2) * 8192 + (nt * 64) * 8;

    __shared__ unsigned short tile[64][65];
#pragma unroll
    for (int p = 0; p < 16; ++p) {
        int r = rg + 4 * p;                     // wave-uniform row
        float av = A[(nt * 64 + r) * 1024 + mt * 64 + c];
        float rn[8];
        *(float4*)&rn[0] = *(const float4*)(rowp + r * 8);
        *(float4*)&rn[4] = *(const float4*)(rowp + r * 8 + 4);
        float h1[8];
#pragma unroll
        for (int h = 0; h < 8; ++h) {
            float v = av * wa[h] + rn[h] + cm[h] + b1v[h];
            h1[h] = v > 0.f ? v : 0.f;
        }
        float o = b3v;
#pragma unroll
        for (int kk = 0; kk < 8; ++kk) {
            float s = b2v[kk];
#pragma unroll
            for (int h = 0; h < 8; ++h) s += h1[h] * w2[kk * 8 + h];
            s = s > 0.f ? s : 0.f;
            o += s * w3v[kk];
        }
        unsigned short us = f2bf(o);
        D0[(nt * 64 + r) * 1024 + mt * 64 + c] = us;
        tile[r][c] = us;
    }
    __syncthreads();
#pragma unroll
    for (int p = 0; p < 16; ++p) {
        int r = rg + 4 * p;
        D1[(mt * 64 + r) * 1024 + nt * 64 + c] = tile[c][r];
    }
}

// ---------------------------------------------------------------------------
// Fused u-compute (MFMA prologue, u-tile -> swizzled LDS) + 4-term main GEMM.
// grid (16 nt, 16 ms), 256 threads (4 waves). P[ms][n][c] partials; u4 global
// written by nt==0 blocks.
__global__ __launch_bounds__(256) void k_gemm2(
    const unsigned short* __restrict__ Abf,
    const unsigned short* __restrict__ xbf,
    const unsigned short* __restrict__ WT,   // this layer: [5][64 c][64 d]
    float* __restrict__ u4, float* __restrict__ P) {
    int nt = blockIdx.x, ms = blockIdx.y;
    int t = threadIdx.x, w = t >> 6, l = t & 63;
    int lr = l & 15, lk = l >> 4, klo = 8 * lk;
    int m0 = ms * 64;
    __shared__ unsigned short uTs[16384];    // [4 j][64 c][64 m] bf16, swizzled

    // ---- u-phase: u[m][c] = sum_d x[m][d] W[d][c] via MFMA ----
    int mrow = m0 + w * 16 + lr;
    bf16x8 xa[2];
    xa[0] = *(const bf16x8*)&xbf[mrow * 64 + klo];
    xa[1] = *(const bf16x8*)&xbf[mrow * 64 + 32 + klo];
    int njmax = (nt == 0) ? 5 : 4;
    for (int j = 0; j < njmax; ++j) {
        f32x4 au[4];
#pragma unroll
        for (int cf = 0; cf < 4; ++cf) au[cf] = (f32x4){0.f, 0.f, 0.f, 0.f};
#pragma unroll
        for (int kk = 0; kk < 2; ++kk)
#pragma unroll
            for (int cf = 0; cf < 4; ++cf) {
                bf16x8 wf = *(const bf16x8*)&WT[(j * 64 + cf * 16 + lr) * 64 + kk * 32 + klo];
                au[cf] = __builtin_amdgcn_mfma_f32_16x16x32_bf16(xa[kk], wf, au[cf], 0, 0, 0);
            }
        if (j < 4) {
#pragma unroll
            for (int cf = 0; cf < 4; ++cf) {
                int cc = cf * 16 + lr;
                us4 pk;
                pk[0] = f2bf(au[cf][0]); pk[1] = f2bf(au[cf][1]);
                pk[2] = f2bf(au[cf][2]); pk[3] = f2bf(au[cf][3]);
                int off = ((j * 64 + cc) * 64 + w * 16 + lk * 4) * 2;
                *(us4*)((char*)uTs + (off ^ ((cc & 7) << 4))) = pk;
            }
        } else {
#pragma unroll
            for (int cf = 0; cf < 4; ++cf)
#pragma unroll
                for (int r = 0; r < 4; ++r)
                    u4[(m0 + w * 16 + lk * 4 + r) * 64 + cf * 16 + lr] = au[cf][r];
        }
    }
    __syncthreads();

    // ---- main: P = a@u0 + aT@u1 + ad@u2 + adT@u3 over this m-window ----
    f32x4 acc[4];
#pragma unroll
    for (int cf = 0; cf < 4; ++cf) acc[cf] = (f32x4){0.f, 0.f, 0.f, 0.f};
    int arow = nt * 64 + w * 16 + lr;
#pragma unroll
    for (int j = 0; j < 4; ++j) {
#pragma unroll
        for (int kk = 0; kk < 2; ++kk) {
            bf16x8 af = *(const bf16x8*)&Abf[j * 1048576 + arow * 1024 + m0 + kk * 32 + klo];
#pragma unroll
            for (int cf = 0; cf < 4; ++cf) {
                int cc = cf * 16 + lr;
                int off = ((j * 64 + cc) * 64 + kk * 32 + klo) * 2;
                bf16x8 bfr = *(const bf16x8*)((char*)uTs + (off ^ ((cc & 7) << 4)));
                acc[cf] = __builtin_amdgcn_mfma_f32_16x16x32_bf16(af, bfr, acc[cf], 0, 0, 0);
            }
        }
    }
    float* Pp = P + ms * 65536;
    int nbase = nt * 64 + w * 16 + lk * 4;
#pragma unroll
    for (int cf = 0; cf < 4; ++cf)
#pragma unroll
        for (int r = 0; r < 4; ++r)
            Pp[(nbase + r) * 64 + cf * 16 + lr] = acc[cf][r];
}

// ---------------------------------------------------------------------------
// mode 0/1: x_next = relu(sum P + u4 + b) -> xbf ; mode 2: out = tg * (...)
__global__ void k_post(const float* __restrict__ P, const float* __restrict__ u4,
                       const float* __restrict__ b, const float* __restrict__ tg,
                       float* __restrict__ out, unsigned short* __restrict__ xbf,
                       int mode) {
    int idx = blockIdx.x * 256 + threadIdx.x;
    int n = idx >> 6, c = idx & 63;
    float s = u4[idx] + b[c];
#pragma unroll
    for (int k = 0; k < 16; ++k) s += P[k * 65536 + idx];
    if (mode < 2) {
        s = fmaxf(s, 0.f);
        xbf[idx] = f2bf(s);
    } else {
        out[idx] = tg[n] * s;
    }
}

// ---------------------------------------------------------------------------
extern "C" void kernel_launch(void* const* d_in, const int* in_sizes, int n_in,
                              void* d_out, int out_size, void* d_ws, size_t ws_size,
                              hipStream_t stream) {
    const float* y         = (const float*)d_in[0];
    const float* adj       = (const float*)d_in[1];
    const float* adj_deriv = (const float*)d_in[2];
    const float* t_grad    = (const float*)d_in[3];
    const float* idx_emb   = (const float*)d_in[4];
    const float* msg_W1    = (const float*)d_in[5];
    const float* msg_b1    = (const float*)d_in[6];
    const float* msg_W2    = (const float*)d_in[7];
    const float* msg_b2    = (const float*)d_in[8];
    const float* msg_W3    = (const float*)d_in[9];
    const float* msg_b3    = (const float*)d_in[10];
    const float* gnn_W     = (const float*)d_in[11];
    const float* gnn_b     = (const float*)d_in[12];

    float* ws = (float*)d_ws;
    float* rc  = ws;                                     // 32768 f
    float* tg  = ws + 32768;                             // 1024 f
    float* u4  = ws + 33792;                             // 65536 f
    float* P   = ws + 99328;                             // 1048576 f
    unsigned short* xbf  = (unsigned short*)(ws + 1147904);  // 65536 us
    unsigned short* WbfT = (unsigned short*)(ws + 1180672);  // 61440 us
    unsigned short* Abf  = (unsigned short*)(ws + 1211392);  // 4194304 us
    // end: ~3.31M floats = 13.3 MB

    k_aux<<<175, 256, 0, stream>>>(idx_emb, msg_W1, rc, t_grad, tg,
                                   y, xbf, gnn_W, WbfT);
    k_msgcvt<<<dim3(16, 16, 2), 256, 0, stream>>>(adj, adj_deriv,
                                                  msg_W1, msg_b1, msg_W2, msg_b2,
                                                  msg_W3, msg_b3, rc, Abf);
    for (int l = 0; l < 3; ++l) {
        k_gemm2<<<dim3(16, 16), 256, 0, stream>>>(Abf, xbf, WbfT + l * 20480, u4, P);
        k_post<<<256, 256, 0, stream>>>(P, u4, gnn_b + l * 64, tg,
                                        (float*)d_out, xbf, (l < 2) ? l : 2);
    }
}